// Round 9
// baseline (52.291 us; speedup 1.0000x reference)
//
#include <hip/hip_runtime.h>
#include <hip/hip_bf16.h>

// HarmonicOscillatorOrbitals: out[b,i,j] = exp(-s^2/2) * H_j(s), s = x[b,i]*k
// x: (65536, 32, 1) fp32; out: (65536, 32, 32) fp32 (= 16,777,216 float4 slots).
//
// Persistent grid-stride version of the round-8 kernel (47.5 us, 5.83 TB/s):
//   - 2048 blocks (8/CU), each wave handles 4 chunks -> 4x fewer
//     wave launches/prologues.
//   - x for chunk i+1 is prefetched BEFORE compute/stores of chunk i: load
//     latency hides under compute; stores of chunk i drain under chunk i+1's
//     compute (loads precede stores in the vmcnt FIFO -> no store drain).
//   - Store pattern byte-identical: slot f = chunkbase + kk*256 + tid, every
//     store wave-contiguous 1 KB. Lockstep 8-chain ILP kept (R7 lesson: the
//     chains MUST advance together; per-chain loops serialize -> 77 us).

#define KPT 8      // float4 slots per thread per chunk
#define NBLK 2048  // persistent blocks (8 per CU)

typedef float f32x4 __attribute__((ext_vector_type(4)));

template <bool GUARD>
__global__ __launch_bounds__(256) void hoo_kernel(
    const float* __restrict__ x,
    const float* __restrict__ omega,
    f32x4* __restrict__ out4,
    unsigned n_quads,
    unsigned stride)  // gridDim.x * 256 * KPT
{
    const unsigned tid  = threadIdx.x;
    const unsigned quad = tid & 7;  // invariant across kk and chunks
    const float k = omega[0];

    unsigned base = blockIdx.x * (256u * KPT) + tid;

    // Prefetch x for the first chunk.
    float sv[KPT];
#pragma unroll
    for (int kk = 0; kk < KPT; ++kk) {
        const unsigned f   = base + (unsigned)kk * 256u;
        const unsigned row = (GUARD ? (f < n_quads ? f : n_quads - 1u) : f) >> 3;
        sv[kk] = x[row];
    }

    while (true) {
        const unsigned next = base + stride;
        const bool have_next = next < n_quads;

        // Capture current chunk's x, then issue next chunk's loads early.
        float s_cur[KPT];
#pragma unroll
        for (int kk = 0; kk < KPT; ++kk) s_cur[kk] = sv[kk];
        if (have_next) {
#pragma unroll
            for (int kk = 0; kk < KPT; ++kk) {
                const unsigned f   = next + (unsigned)kk * 256u;
                const unsigned row = (GUARD ? (f < n_quads ? f : n_quads - 1u) : f) >> 3;
                sv[kk] = x[row];
            }
        }

        float env[KPT], twox[KPT], h0[KPT], h1[KPT], h2[KPT], h3[KPT];
#pragma unroll
        for (int kk = 0; kk < KPT; ++kk) {
            const float s = s_cur[kk] * k;
            env[kk] = __expf(-0.5f * (s * s));
            const float tx = 2.0f * s;
            twox[kk] = tx;
            h0[kk] = 1.0f;                       // H_0
            h1[kk] = tx;                         // H_1
            h2[kk] = tx * tx - 2.0f;             // H_2
            h3[kk] = tx * h2[kk] - 4.0f * tx;    // H_3 (4*H_1 = 4*tx)
        }

        // Lockstep: all 8 chains advance 4 Hermite orders per iteration.
        float c = 6.0f;  // 2*(k-1) for k=4
        for (unsigned it = 0; it < quad; ++it) {
            const float c1 = c + 2.0f;
            const float c2 = c + 4.0f;
            const float c3 = c + 6.0f;
#pragma unroll
            for (int kk = 0; kk < KPT; ++kk) {
                const float tx = twox[kk];
                const float n0 = tx * h3[kk] - c  * h2[kk];
                const float n1 = tx * n0     - c1 * h3[kk];
                const float n2 = tx * n1     - c2 * n0;
                const float n3 = tx * n2     - c3 * n1;
                h0[kk] = n0; h1[kk] = n1; h2[kk] = n2; h3[kk] = n3;
            }
            c += 8.0f;
        }

#pragma unroll
        for (int kk = 0; kk < KPT; ++kk) {
            const unsigned f = base + (unsigned)kk * 256u;
            if (!GUARD || f < n_quads) {
                f32x4 v;
                v.x = env[kk] * h0[kk];
                v.y = env[kk] * h1[kk];
                v.z = env[kk] * h2[kk];
                v.w = env[kk] * h3[kk];
                out4[f] = v;
            }
        }

        if (!have_next) break;
        base = next;
    }
}

extern "C" void kernel_launch(void* const* d_in, const int* in_sizes, int n_in,
                              void* d_out, int out_size, void* d_ws, size_t ws_size,
                              hipStream_t stream) {
    const float* x     = (const float*)d_in[0];
    const float* omega = (const float*)d_in[1];
    f32x4* out4        = (f32x4*)d_out;

    const unsigned n_rows  = (unsigned)in_sizes[0];  // 2,097,152
    const unsigned n_quads = n_rows * 8u;            // 16,777,216 float4 slots

    const unsigned spb = 256u * KPT;                           // 2048 slots/block/chunk
    const unsigned blocks_needed = (n_quads + spb - 1) / spb;  // 8192
    const unsigned grid = blocks_needed < NBLK ? blocks_needed : NBLK;
    const unsigned stride = grid * spb;

    if (n_quads % spb == 0) {
        hoo_kernel<false><<<grid, 256, 0, stream>>>(x, omega, out4, n_quads, stride);
    } else {
        hoo_kernel<true><<<grid, 256, 0, stream>>>(x, omega, out4, n_quads, stride);
    }
}

// Round 10
// 47.780 us; speedup vs baseline: 1.0944x; 1.0944x over previous
//
#include <hip/hip_runtime.h>
#include <hip/hip_bf16.h>

// HarmonicOscillatorOrbitals: out[b,i,j] = exp(-s^2/2) * H_j(s), s = x[b,i]*k
// x: (65536, 32, 1) fp32; out: (65536, 32, 32) fp32 (= 16,777,216 float4 slots).
//
// BEST structure (round 8: 47.5 us, 5.83 TB/s = 93% of 6.29 TB/s copy ceiling).
// Reverted from round 9's persistent/prefetch variant (52.3 us — wave churn is
// NOT a limiter; retiring waves drain stores for free while fresh waves issue).
//
// Invariants found by A/B (do not change):
//   - slot f = blockIdx.x*2048 + kk*256 + tid: every store wave-contiguous 1 KB
//     (lane-strided 128 B rows were 2.5 TB/s; this layout is the big win).
//   - 8 LOCKSTEP chains per thread, single divergent loop, trip = quad = tid&7:
//     8-way FMA ILP. Per-chain loops serialize the FMA deps -> 77 us (R7).
//   - Regular write-back stores: NT no-allocate measured slower (R5/R6 A/B).
//   - GUARD templated out (grid divides exactly); __expf (tolerance ~bf16).

#define KPT 8  // float4 slots per thread

typedef float f32x4 __attribute__((ext_vector_type(4)));

template <bool GUARD>
__global__ __launch_bounds__(256) void hoo_kernel(
    const float* __restrict__ x,
    const float* __restrict__ omega,
    f32x4* __restrict__ out4,
    unsigned n_quads)
{
    const unsigned tid  = threadIdx.x;
    const unsigned quad = tid & 7;  // same for all KPT slots (256 % 8 == 0)
    const unsigned base = blockIdx.x * (256u * KPT) + tid;

    const float k = omega[0];

    float env[KPT], twox[KPT];
    float h0[KPT], h1[KPT], h2[KPT], h3[KPT];

#pragma unroll
    for (int kk = 0; kk < KPT; ++kk) {
        const unsigned f   = base + (unsigned)kk * 256u;
        const unsigned row = (GUARD ? (f < n_quads ? f : n_quads - 1u) : f) >> 3;
        const float s = x[row] * k;
        env[kk]  = __expf(-0.5f * (s * s));
        const float tx = 2.0f * s;
        twox[kk] = tx;
        // H_0=1, H_1=2x, H_2, H_3
        h0[kk] = 1.0f;
        h1[kk] = tx;
        h2[kk] = tx * h1[kk] - 2.0f;
        h3[kk] = tx * h2[kk] - 4.0f * h1[kk];
    }

    // Advance all 8 chains 4 Hermite orders per iteration, in lockstep;
    // trip count = quad (divergent across lanes only). 8-way FMA ILP.
    float c = 6.0f;  // 2*(k-1) for k=4
    for (unsigned it = 0; it < quad; ++it) {
        const float c1 = c + 2.0f;
        const float c2 = c + 4.0f;
        const float c3 = c + 6.0f;
#pragma unroll
        for (int kk = 0; kk < KPT; ++kk) {
            const float tx = twox[kk];
            const float n0 = tx * h3[kk] - c  * h2[kk];
            const float n1 = tx * n0     - c1 * h3[kk];
            const float n2 = tx * n1     - c2 * n0;
            const float n3 = tx * n2     - c3 * n1;
            h0[kk] = n0; h1[kk] = n1; h2[kk] = n2; h3[kk] = n3;
        }
        c += 8.0f;
    }

#pragma unroll
    for (int kk = 0; kk < KPT; ++kk) {
        const unsigned f = base + (unsigned)kk * 256u;
        if (!GUARD || f < n_quads) {
            f32x4 v;
            v.x = env[kk] * h0[kk];
            v.y = env[kk] * h1[kk];
            v.z = env[kk] * h2[kk];
            v.w = env[kk] * h3[kk];
            out4[f] = v;
        }
    }
}

extern "C" void kernel_launch(void* const* d_in, const int* in_sizes, int n_in,
                              void* d_out, int out_size, void* d_ws, size_t ws_size,
                              hipStream_t stream) {
    const float* x     = (const float*)d_in[0];
    const float* omega = (const float*)d_in[1];
    f32x4* out4        = (f32x4*)d_out;

    const unsigned n_rows  = (unsigned)in_sizes[0];  // 2,097,152
    const unsigned n_quads = n_rows * 8u;            // 16,777,216 float4 slots

    const unsigned spb = 256u * KPT;                 // 2048 slots per block
    const unsigned grid = (n_quads + spb - 1) / spb; // 8192

    if (n_quads % spb == 0) {
        hoo_kernel<false><<<grid, 256, 0, stream>>>(x, omega, out4, n_quads);
    } else {
        hoo_kernel<true><<<grid, 256, 0, stream>>>(x, omega, out4, n_quads);
    }
}